// Round 4
// baseline (1073.928 us; speedup 1.0000x reference)
//
#include <hip/hip_runtime.h>
#include <hip/hip_bf16.h>

#define T   512
#define D   256
#define H   4
#define NN  8192
#define V   256
#define EPSF 1e-5f
#define QKS 4          // split-K for scores GEMM
#define DSPLIT 32      // split-K for decoder GEMM
#define N_LAYER 6

typedef __bf16 bf16;
typedef __attribute__((__ext_vector_type__(8))) __bf16 bf16x8;
typedef __attribute__((__ext_vector_type__(4))) __bf16 bf16x4;
typedef __attribute__((__ext_vector_type__(4))) float  f32x4;

// ---------------- block-wide sum over 256 threads ---------------------------
__device__ __forceinline__ float blk_sum256(float v, float* red) {
#pragma unroll
    for (int off = 32; off > 0; off >>= 1) v += __shfl_down(v, off, 64);
    int lane = threadIdx.x & 63, w = threadIdx.x >> 6;
    __syncthreads();
    if (lane == 0) red[w] = v;
    __syncthreads();
    return red[0] + red[1] + red[2] + red[3];
}

// ---------------- transpose + f32->bf16 convert (32x32 tiles) ---------------
__global__ __launch_bounds__(256) void tcvt_k(const float* __restrict__ in,
                                              bf16* __restrict__ out, int R, int C) {
    __shared__ float t[32][33];
    size_t hoff = (size_t)blockIdx.z * R * C;
    int c0 = blockIdx.x * 32, r0 = blockIdx.y * 32;
    int x = threadIdx.x & 31, y = threadIdx.x >> 5;
#pragma unroll
    for (int p = 0; p < 4; ++p)
        t[y + 8 * p][x] = in[hoff + (size_t)(r0 + y + 8 * p) * C + c0 + x];
    __syncthreads();
#pragma unroll
    for (int p = 0; p < 4; ++p)
        out[hoff + (size_t)(c0 + y + 8 * p) * R + r0 + x] = (bf16)t[x][y + 8 * p];
}

// ---------------- RoPE cos/sin HALF tables (pairs share angle) --------------
// cosH[t][k] = cos(angle(t, n=2k)), k < NN/2
__global__ __launch_bounds__(256) void rope_tab_k(bf16* __restrict__ cosH,
                                                  bf16* __restrict__ sinH) {
    int k = blockIdx.x * 256 + threadIdx.x;     // 0..NN/2-1
    int t = blockIdx.y;
    float q = (float)(2 * k);
    float f = exp2f(q * (-16.0f / (float)NN)) * 0.15915494309189535f;
    float u = fmodf((float)t * f, 1.0f);
    float a = u * 6.283185307179586f;
    cosH[(size_t)t * (NN / 2) + k] = (bf16)cosf(a);
    sinH[(size_t)t * (NN / 2) + k] = (bf16)sinf(a);
}

// ---------------- x = LN(embed[idx]) (writes f32 + bf16 + bf16^T) -----------
__global__ __launch_bounds__(256) void embed_ln_k(const int* __restrict__ idx,
                                                  const float* __restrict__ embed,
                                                  float* __restrict__ x,
                                                  bf16* __restrict__ xb,
                                                  bf16* __restrict__ xbT) {
    __shared__ float red[4];
    int t = blockIdx.x, d = threadIdx.x;
    float e = embed[(size_t)idx[t] * D + d];
    float m = blk_sum256(e, red) * (1.0f / D);
    float df = e - m;
    float vv = blk_sum256(df * df, red) * (1.0f / D);
    float r = df * rsqrtf(vv + EPSF);
    x[(size_t)t * D + d] = r;
    xb[(size_t)t * D + d] = (bf16)r;
    xbT[(size_t)d * T + t] = (bf16)r;
}

// ---------------- MFMA 128x128 core, double-buffered + reg prefetch ---------
// A staged row-major [m][k], B staged as rows of B^T: [n][k]; both k-contig.
// Per kstep: issue next loads -> ds_read+MFMA current -> ds_write next -> bar.
__device__ __forceinline__ void gemm_core(const bf16* __restrict__ Ap, size_t lda,
                                          const bf16* __restrict__ Bp, size_t ldb,
                                          int ksteps,
                                          bf16 (*As)[128][40], bf16 (*Bs)[128][40],
                                          f32x4 acc[4][4], int tid) {
    int lane = tid & 63, wid = tid >> 6;
    int wr = (wid >> 1) * 64, wc = (wid & 1) * 64;
    int fr = lane & 15;
    int fk = (lane >> 4) * 8;
    int r0 = tid >> 2;            // 0..63
    int kq = (tid & 3) * 8;
    const bf16* a0 = Ap + (size_t)r0 * lda + kq;
    const bf16* a1 = Ap + (size_t)(r0 + 64) * lda + kq;
    const bf16* b0 = Bp + (size_t)r0 * ldb + kq;
    const bf16* b1 = Bp + (size_t)(r0 + 64) * ldb + kq;
    uint4 pa0 = *(const uint4*)a0, pa1 = *(const uint4*)a1;
    uint4 pb0 = *(const uint4*)b0, pb1 = *(const uint4*)b1;
    *(uint4*)&As[0][r0][kq]      = pa0;  *(uint4*)&As[0][r0 + 64][kq] = pa1;
    *(uint4*)&Bs[0][r0][kq]      = pb0;  *(uint4*)&Bs[0][r0 + 64][kq] = pb1;
    __syncthreads();
    for (int ks = 0; ks < ksteps; ++ks) {
        int cur = ks & 1;
        if (ks + 1 < ksteps) {          // issue next-tile loads (latency hidden by MFMA)
            size_t o = (size_t)(ks + 1) * 32;
            pa0 = *(const uint4*)(a0 + o);  pa1 = *(const uint4*)(a1 + o);
            pb0 = *(const uint4*)(b0 + o);  pb1 = *(const uint4*)(b1 + o);
        }
        bf16x8 af[4], bfr[4];
#pragma unroll
        for (int i = 0; i < 4; ++i) {
            af[i]  = *(const bf16x8*)&As[cur][wr + i * 16 + fr][fk];
            bfr[i] = *(const bf16x8*)&Bs[cur][wc + i * 16 + fr][fk];
        }
#pragma unroll
        for (int i = 0; i < 4; ++i)
#pragma unroll
            for (int jj = 0; jj < 4; ++jj)
                acc[i][jj] = __builtin_amdgcn_mfma_f32_16x16x32_bf16(
                    af[i], bfr[jj], acc[i][jj], 0, 0, 0);
        if (ks + 1 < ksteps) {          // write-late: vmcnt wait lands after MFMA
            int nxt = cur ^ 1;
            *(uint4*)&As[nxt][r0][kq]      = pa0;  *(uint4*)&As[nxt][r0 + 64][kq] = pa1;
            *(uint4*)&Bs[nxt][r0][kq]      = pb0;  *(uint4*)&Bs[nxt][r0 + 64][kq] = pb1;
        }
        __syncthreads();
    }
}

// ---------------- encoder GEMM + relu (+RoPE / +xy product) -----------------
// MODE 0: xs = relu(C); qr = rope(xs).  MODE 1: xs *= relu(C)  (xy in place)
template <int MODE>
__global__ __launch_bounds__(256) void enc_mfma_k(const bf16* __restrict__ A,
                                                  const bf16* __restrict__ Wt,
                                                  bf16* __restrict__ xs,
                                                  bf16* __restrict__ qr,
                                                  const bf16* __restrict__ cosH,
                                                  const bf16* __restrict__ sinH,
                                                  int aHeadStride) {
    __shared__ bf16 As[2][128][40];
    __shared__ bf16 Bs[2][128][40];
    int h = blockIdx.z;
    int row0 = blockIdx.y * 128, col0 = blockIdx.x * 128;
    const bf16* Ap = A + (size_t)h * aHeadStride + (size_t)row0 * D;
    const bf16* Bp = Wt + ((size_t)h * NN + col0) * D;
    int tid = threadIdx.x;
    f32x4 acc[4][4];
#pragma unroll
    for (int i = 0; i < 4; ++i)
#pragma unroll
        for (int j = 0; j < 4; ++j) acc[i][j] = f32x4{0.f, 0.f, 0.f, 0.f};
    gemm_core(Ap, D, Bp, D, D / 32, As, Bs, acc, tid);

    int lane = tid & 63, wid = tid >> 6;
    int wr = (wid >> 1) * 64, wc = (wid & 1) * 64;
    int fr = lane & 15, fq = lane >> 4;
#pragma unroll
    for (int mi = 0; mi < 4; ++mi)
#pragma unroll
        for (int ni = 0; ni < 4; ++ni) {
            int n = col0 + wc + ni * 16 + fr;
            int mbase = row0 + wr + mi * 16 + fq * 4;
#pragma unroll
            for (int j = 0; j < 4; ++j) {
                int m = mbase + j;
                size_t base = ((size_t)h * T + m) * NN + n;
                float v = fmaxf((float)acc[mi][ni][j], 0.0f);
                if (MODE == 0) {
                    float p = __shfl_xor(v, 1, 64);   // partner col n^1
                    float cs = (float)cosH[(size_t)m * (NN / 2) + (n >> 1)];
                    float sn = (float)sinH[(size_t)m * (NN / 2) + (n >> 1)];
                    float qv = v * cs + ((n & 1) ? p * sn : -p * sn);
                    xs[base] = (bf16)v;
                    qr[base] = (bf16)qv;
                } else {
                    float xo = (float)xs[base];
                    xs[base] = (bf16)(xo * v);
                }
            }
        }
}

// ---------------- scores GEMM: spart[ks][h][t][s] (lower-tri tiles) ---------
__global__ __launch_bounds__(256) void qq_mfma_k(const bf16* __restrict__ qrb,
                                                 float* __restrict__ spart) {
    __shared__ bf16 As[2][128][40];
    __shared__ bf16 Bs[2][128][40];
    static const int TI[10] = {0,1,1,2,2,2,3,3,3,3};
    static const int TJ[10] = {0,0,1,0,1,2,0,1,2,3};
    int ti = TI[blockIdx.x], tj = TJ[blockIdx.x];
    int h = blockIdx.y, ks = blockIdx.z;
    const bf16* Q = qrb + (size_t)h * T * NN + (size_t)ks * (NN / QKS);
    const bf16* Ap = Q + (size_t)(ti * 128) * NN;
    const bf16* Bp = Q + (size_t)(tj * 128) * NN;
    int tid = threadIdx.x;
    f32x4 acc[4][4];
#pragma unroll
    for (int i = 0; i < 4; ++i)
#pragma unroll
        for (int j = 0; j < 4; ++j) acc[i][j] = f32x4{0.f, 0.f, 0.f, 0.f};
    gemm_core(Ap, NN, Bp, NN, (NN / QKS) / 32, As, Bs, acc, tid);

    int lane = tid & 63, wid = tid >> 6;
    int wr = (wid >> 1) * 64, wc = (wid & 1) * 64;
    int fr = lane & 15, fq = lane >> 4;
    float* outp = spart + (size_t)(ks * H + h) * T * T;
#pragma unroll
    for (int mi = 0; mi < 4; ++mi)
#pragma unroll
        for (int ni = 0; ni < 4; ++ni) {
            int s = tj * 128 + wc + ni * 16 + fr;
            int mbase = ti * 128 + wr + mi * 16 + fq * 4;
#pragma unroll
            for (int j = 0; j < 4; ++j)
                outp[(size_t)(mbase + j) * T + s] = acc[mi][ni][j];
        }
}

// ---------------- sb[h][t][s] = bf16(sum_ks spart), strict causal mask ------
// grid (T/2, H), 256 thr: 2 rows x 128 lanes, float4 per lane
__global__ __launch_bounds__(256) void mask_cvt_k(const float* __restrict__ spart,
                                                  bf16* __restrict__ sb) {
    int t = blockIdx.x * 2 + (threadIdx.x >> 7);
    int h = blockIdx.y;
    int l = threadIdx.x & 127;
    int s = l * 4;
    const float* s0 = spart + ((size_t)h * T + t) * T + s;
    const size_t st = (size_t)H * T * T;
    float4 w0 = *(const float4*)(s0);
    float4 w1 = *(const float4*)(s0 + st);
    float4 w2 = *(const float4*)(s0 + 2 * st);
    float4 w3 = *(const float4*)(s0 + 3 * st);
    bf16x4 o;
    o[0] = (bf16)((s + 0 < t) ? (w0.x + w1.x + w2.x + w3.x) : 0.0f);
    o[1] = (bf16)((s + 1 < t) ? (w0.y + w1.y + w2.y + w3.y) : 0.0f);
    o[2] = (bf16)((s + 2 < t) ? (w0.z + w1.z + w2.z + w3.z) : 0.0f);
    o[3] = (bf16)((s + 3 < t) ? (w0.w + w1.w + w2.w + w3.w) : 0.0f);
    *(bf16x4*)(sb + ((size_t)h * T + t) * T + s) = o;
}

// ---------------- av: ykv_pre[h][t][d] = sum_s sb[t,s] * x[s,d] (MFMA) ------
__global__ __launch_bounds__(256) void av_mfma_k(const bf16* __restrict__ sb,
                                                 const bf16* __restrict__ xbT,
                                                 float* __restrict__ ykv_pre) {
    __shared__ bf16 As[2][128][40];
    __shared__ bf16 Bs[2][128][40];
    int h = blockIdx.z;
    int ti = blockIdx.y;
    int row0 = ti * 128, col0 = blockIdx.x * 128;
    const bf16* Ap = sb + ((size_t)h * T + row0) * T;
    const bf16* Bp = xbT + (size_t)col0 * T;
    int tid = threadIdx.x;
    f32x4 acc[4][4];
#pragma unroll
    for (int i = 0; i < 4; ++i)
#pragma unroll
        for (int j = 0; j < 4; ++j) acc[i][j] = f32x4{0.f, 0.f, 0.f, 0.f};
    // causal: sb[t][s]==0 for s>=t, so only need k < (ti+1)*128
    gemm_core(Ap, T, Bp, T, (ti + 1) * 4, As, Bs, acc, tid);

    int lane = tid & 63, wid = tid >> 6;
    int wr = (wid >> 1) * 64, wc = (wid & 1) * 64;
    int fr = lane & 15, fq = lane >> 4;
#pragma unroll
    for (int mi = 0; mi < 4; ++mi)
#pragma unroll
        for (int ni = 0; ni < 4; ++ni) {
            int n = col0 + wc + ni * 16 + fr;
            int mbase = row0 + wr + mi * 16 + fq * 4;
#pragma unroll
            for (int j = 0; j < 4; ++j)
                ykv_pre[((size_t)h * T + (mbase + j)) * D + n] = acc[mi][ni][j];
        }
}

// ---------------- ykv LN: ykvb = LN(ykv_pre) --------------------------------
__global__ __launch_bounds__(256) void ykv_ln_k(const float* __restrict__ ykv_pre,
                                                bf16* __restrict__ ykvb) {
    __shared__ float red[4];
    int t = blockIdx.x, h = blockIdx.y, d = threadIdx.x;
    float a = ykv_pre[((size_t)h * T + t) * D + d];
    float m = blk_sum256(a, red) * (1.0f / D);
    float df = a - m;
    float vv = blk_sum256(df * df, red) * (1.0f / D);
    ykvb[((size_t)h * T + t) * D + d] = (bf16)(df * rsqrtf(vv + EPSF));
}

// ---------------- decoder GEMM (split-K) ------------------------------------
__global__ __launch_bounds__(256) void dec_mfma_k(const bf16* __restrict__ xyb,
                                                  const bf16* __restrict__ decT,
                                                  float* __restrict__ ypart) {
    __shared__ bf16 As[2][128][40];
    __shared__ bf16 Bs[2][128][40];
    int ks = blockIdx.z;
    int cbeg = ks * ((H * NN) / DSPLIT);   // 1024-wide slices, within one head
    int h = cbeg >> 13, n0 = cbeg & (NN - 1);
    int row0 = blockIdx.y * 128, col0 = blockIdx.x * 128;
    const bf16* Ap = xyb + ((size_t)h * T + row0) * NN + n0;
    const bf16* Bp = decT + (size_t)col0 * (H * NN) + cbeg;
    int tid = threadIdx.x;
    f32x4 acc[4][4];
#pragma unroll
    for (int i = 0; i < 4; ++i)
#pragma unroll
        for (int j = 0; j < 4; ++j) acc[i][j] = f32x4{0.f, 0.f, 0.f, 0.f};
    gemm_core(Ap, NN, Bp, H * NN, (H * NN / DSPLIT) / 32, As, Bs, acc, tid);

    int lane = tid & 63, wid = tid >> 6;
    int wr = (wid >> 1) * 64, wc = (wid & 1) * 64;
    int fr = lane & 15, fq = lane >> 4;
#pragma unroll
    for (int mi = 0; mi < 4; ++mi)
#pragma unroll
        for (int ni = 0; ni < 4; ++ni) {
            int n = col0 + wc + ni * 16 + fr;
            int mbase = row0 + wr + mi * 16 + fq * 4;
#pragma unroll
            for (int j = 0; j < 4; ++j)
                ypart[((size_t)ks * T + (mbase + j)) * D + n] = acc[mi][ni][j];
        }
}

// ---------------- y = LN(sum ypart); x = LN(x + y); bf16 + bf16^T copies ----
__global__ __launch_bounds__(256) void final_ln_k(const float* __restrict__ ypart,
                                                  float* __restrict__ x,
                                                  bf16* __restrict__ xb,
                                                  bf16* __restrict__ xbT) {
    __shared__ float red[4];
    int t = blockIdx.x, d = threadIdx.x;
    float ys = 0.0f;
#pragma unroll
    for (int ks = 0; ks < DSPLIT; ++ks) ys += ypart[((size_t)ks * T + t) * D + d];
    float m = blk_sum256(ys, red) * (1.0f / D);
    float df = ys - m;
    float vv = blk_sum256(df * df, red) * (1.0f / D);
    float yln = df * rsqrtf(vv + EPSF);
    float val = x[(size_t)t * D + d] + yln;
    float m2 = blk_sum256(val, red) * (1.0f / D);
    float df2 = val - m2;
    float v2 = blk_sum256(df2 * df2, red) * (1.0f / D);
    float r = df2 * rsqrtf(v2 + EPSF);
    x[(size_t)t * D + d] = r;
    xb[(size_t)t * D + d] = (bf16)r;
    xbT[(size_t)d * T + t] = (bf16)r;
}

// ---------------- logits = x @ lm_head (f32) --------------------------------
__global__ __launch_bounds__(256) void logits_k(const float* __restrict__ x,
                                                const float* __restrict__ lm,
                                                float* __restrict__ out) {
    int t = blockIdx.x, v = threadIdx.x;
    float a = 0.0f;
    for (int d = 0; d < D; ++d)
        a = fmaf(x[(size_t)t * D + d], lm[(size_t)d * V + v], a);
    out[(size_t)t * V + v] = a;
}

extern "C" void kernel_launch(void* const* d_in, const int* in_sizes, int n_in,
                              void* d_out, int out_size, void* d_ws, size_t ws_size,
                              hipStream_t stream) {
    const int*   idx       = (const int*)d_in[0];
    const float* embed     = (const float*)d_in[1];
    const float* encoder   = (const float*)d_in[2];
    const float* encoder_v = (const float*)d_in[3];
    const float* decoder   = (const float*)d_in[4];
    const float* lm_head   = (const float*)d_in[5];
    float* out = (float*)d_out;

    // ---- workspace layout (~146 MB) ----
    char* W = (char*)d_ws;
    float* x       = (float*)W; W += (size_t)T * D * 4;
    float* scratch = (float*)W; W += (size_t)QKS * H * T * T * 4;  // spart / ykv_pre / ypart union
    bf16* xb    = (bf16*)W; W += (size_t)T * D * 2;
    bf16* xbT   = (bf16*)W; W += (size_t)D * T * 2;
    bf16* sb    = (bf16*)W; W += (size_t)H * T * T * 2;
    bf16* ykvb  = (bf16*)W; W += (size_t)H * T * D * 2;
    bf16* encT  = (bf16*)W; W += (size_t)H * NN * D * 2;
    bf16* encVT = (bf16*)W; W += (size_t)H * NN * D * 2;
    bf16* decT  = (bf16*)W; W += (size_t)D * H * NN * 2;
    bf16* cosH  = (bf16*)W; W += (size_t)T * (NN / 2) * 2;
    bf16* sinH  = (bf16*)W; W += (size_t)T * (NN / 2) * 2;
    bf16* xs    = (bf16*)W; W += (size_t)H * T * NN * 2;
    bf16* qr    = (bf16*)W; W += (size_t)H * T * NN * 2;

    // ---- one-time per launch: weight transpose+convert, RoPE tables ----
    tcvt_k<<<dim3(NN / 32, D / 32, H), 256, 0, stream>>>(encoder, encT, D, NN);
    tcvt_k<<<dim3(NN / 32, D / 32, H), 256, 0, stream>>>(encoder_v, encVT, D, NN);
    tcvt_k<<<dim3(D / 32, (H * NN) / 32, 1), 256, 0, stream>>>(decoder, decT, H * NN, D);
    rope_tab_k<<<dim3((NN / 2) / 256, T), 256, 0, stream>>>(cosH, sinH);

    embed_ln_k<<<T, 256, 0, stream>>>(idx, embed, x, xb, xbT);

    for (int layer = 0; layer < N_LAYER; ++layer) {
        enc_mfma_k<0><<<dim3(NN / 128, T / 128, H), 256, 0, stream>>>(
            xb, encT, xs, qr, cosH, sinH, 0);
        qq_mfma_k<<<dim3(10, H, QKS), 256, 0, stream>>>(qr, scratch);
        mask_cvt_k<<<dim3(T / 2, H), 256, 0, stream>>>(scratch, sb);
        av_mfma_k<<<dim3(D / 128, T / 128, H), 256, 0, stream>>>(sb, xbT, scratch);
        ykv_ln_k<<<dim3(T, H), 256, 0, stream>>>(scratch, ykvb);
        enc_mfma_k<1><<<dim3(NN / 128, T / 128, H), 256, 0, stream>>>(
            ykvb, encVT, xs, nullptr, nullptr, nullptr, T * D);
        dec_mfma_k<<<dim3(D / 128, T / 128, DSPLIT), 256, 0, stream>>>(
            xs, decT, scratch);
        final_ln_k<<<T, 256, 0, stream>>>(scratch, x, xb, xbT);
    }

    logits_k<<<T, 256, 0, stream>>>(x, lm_head, out);
}

// Round 5
// 957.972 us; speedup vs baseline: 1.1210x; 1.1210x over previous
//
#include <hip/hip_runtime.h>
#include <hip/hip_bf16.h>

#define T   512
#define D   256
#define H   4
#define NN  8192
#define V   256
#define EPSF 1e-5f
#define QKS 4          // split-K for scores GEMM
#define DSPLIT 32      // split-K for decoder GEMM
#define N_LAYER 6

typedef __bf16 bf16;
typedef __attribute__((__ext_vector_type__(8))) __bf16 bf16x8;
typedef __attribute__((__ext_vector_type__(4))) __bf16 bf16x4;
typedef __attribute__((__ext_vector_type__(4))) float  f32x4;

// ---------------- block-wide sum over 256 threads ---------------------------
__device__ __forceinline__ float blk_sum256(float v, float* red) {
#pragma unroll
    for (int off = 32; off > 0; off >>= 1) v += __shfl_down(v, off, 64);
    int lane = threadIdx.x & 63, w = threadIdx.x >> 6;
    __syncthreads();
    if (lane == 0) red[w] = v;
    __syncthreads();
    return red[0] + red[1] + red[2] + red[3];
}

// ---------------- transpose + f32->bf16 convert (32x32 tiles) ---------------
__global__ __launch_bounds__(256) void tcvt_k(const float* __restrict__ in,
                                              bf16* __restrict__ out, int R, int C) {
    __shared__ float t[32][33];
    size_t hoff = (size_t)blockIdx.z * R * C;
    int c0 = blockIdx.x * 32, r0 = blockIdx.y * 32;
    int x = threadIdx.x & 31, y = threadIdx.x >> 5;
#pragma unroll
    for (int p = 0; p < 4; ++p)
        t[y + 8 * p][x] = in[hoff + (size_t)(r0 + y + 8 * p) * C + c0 + x];
    __syncthreads();
#pragma unroll
    for (int p = 0; p < 4; ++p)
        out[hoff + (size_t)(c0 + y + 8 * p) * R + r0 + x] = (bf16)t[x][y + 8 * p];
}

// ---------------- RoPE cos/sin HALF tables (pairs share angle) --------------
__global__ __launch_bounds__(256) void rope_tab_k(bf16* __restrict__ cosH,
                                                  bf16* __restrict__ sinH) {
    int k = blockIdx.x * 256 + threadIdx.x;     // 0..NN/2-1
    int t = blockIdx.y;
    float q = (float)(2 * k);
    float f = exp2f(q * (-16.0f / (float)NN)) * 0.15915494309189535f;
    float u = fmodf((float)t * f, 1.0f);
    float a = u * 6.283185307179586f;
    cosH[(size_t)t * (NN / 2) + k] = (bf16)cosf(a);
    sinH[(size_t)t * (NN / 2) + k] = (bf16)sinf(a);
}

// ---------------- x = LN(embed[idx]) (writes f32 + bf16 + bf16^T) -----------
__global__ __launch_bounds__(256) void embed_ln_k(const int* __restrict__ idx,
                                                  const float* __restrict__ embed,
                                                  float* __restrict__ x,
                                                  bf16* __restrict__ xb,
                                                  bf16* __restrict__ xbT) {
    __shared__ float red[4];
    int t = blockIdx.x, d = threadIdx.x;
    float e = embed[(size_t)idx[t] * D + d];
    float m = blk_sum256(e, red) * (1.0f / D);
    float df = e - m;
    float vv = blk_sum256(df * df, red) * (1.0f / D);
    float r = df * rsqrtf(vv + EPSF);
    x[(size_t)t * D + d] = r;
    xb[(size_t)t * D + d] = (bf16)r;
    xbT[(size_t)d * T + t] = (bf16)r;
}

// ---------------- MFMA 64x64 core, single-buffered, 4 waves (2x2) -----------
// A staged row-major [m][k], B staged as rows of B^T: [n][k]; both k-contig.
__device__ __forceinline__ void gemm_core64(const bf16* __restrict__ Ap, size_t lda,
                                            const bf16* __restrict__ Bp, size_t ldb,
                                            int ksteps,
                                            bf16 (*As)[40], bf16 (*Bs)[40],
                                            f32x4 acc[2][2], int tid) {
    int lane = tid & 63, wid = tid >> 6;
    int wr = (wid >> 1) * 32, wc = (wid & 1) * 32;
    int fr = lane & 15, fk = (lane >> 4) * 8;
    int r0 = tid >> 2, kq = (tid & 3) * 8;
    const bf16* ag = Ap + (size_t)r0 * lda + kq;
    const bf16* bg = Bp + (size_t)r0 * ldb + kq;
    for (int ks = 0; ks < ksteps; ++ks) {
        size_t o = (size_t)ks * 32;
        *(uint4*)&As[r0][kq] = *(const uint4*)(ag + o);
        *(uint4*)&Bs[r0][kq] = *(const uint4*)(bg + o);
        __syncthreads();
        bf16x8 af[2], bfr[2];
#pragma unroll
        for (int i = 0; i < 2; ++i) {
            af[i]  = *(const bf16x8*)&As[wr + i * 16 + fr][fk];
            bfr[i] = *(const bf16x8*)&Bs[wc + i * 16 + fr][fk];
        }
#pragma unroll
        for (int i = 0; i < 2; ++i)
#pragma unroll
            for (int j = 0; j < 2; ++j)
                acc[i][j] = __builtin_amdgcn_mfma_f32_16x16x32_bf16(
                    af[i], bfr[j], acc[i][j], 0, 0, 0);
        __syncthreads();
    }
}

// ---------------- encoder GEMM + relu (+RoPE / *old), coalesced epilogue ----
// MODE 0: xs = relu(C); qr = rope(xs).  MODE 1: xs *= relu(C)  (xy in place)
template <int MODE>
__global__ __launch_bounds__(256) void enc_mfma_k(const bf16* __restrict__ A,
                                                  const bf16* __restrict__ Wt,
                                                  bf16* __restrict__ xs,
                                                  bf16* __restrict__ qr,
                                                  const bf16* __restrict__ cosH,
                                                  const bf16* __restrict__ sinH,
                                                  int aHeadStride) {
    __shared__ __align__(16) char smem[10240];
    bf16 (*As)[40] = (bf16(*)[40])smem;
    bf16 (*Bs)[40] = (bf16(*)[40])(smem + 5120);
    bf16 (*Ot)[76] = (bf16(*)[76])smem;           // epilogue reuse, 9728 B
    int h = blockIdx.z;
    int row0 = blockIdx.y * 64, col0 = blockIdx.x * 64;
    const bf16* Ap = A + (size_t)h * aHeadStride + (size_t)row0 * D;
    const bf16* Bp = Wt + ((size_t)h * NN + col0) * D;
    int tid = threadIdx.x;
    f32x4 acc[2][2];
#pragma unroll
    for (int i = 0; i < 2; ++i)
#pragma unroll
        for (int j = 0; j < 2; ++j) acc[i][j] = f32x4{0.f, 0.f, 0.f, 0.f};
    gemm_core64(Ap, D, Bp, D, D / 32, As, Bs, acc, tid);
    // core ends with __syncthreads(): LDS free for reuse

    int lane = tid & 63, wid = tid >> 6;
    int wr = (wid >> 1) * 32, wc = (wid & 1) * 32;
    int fr = lane & 15, fq = lane >> 4;
    float vv[2][2][4];
#pragma unroll
    for (int mi = 0; mi < 2; ++mi)
#pragma unroll
        for (int ni = 0; ni < 2; ++ni)
#pragma unroll
            for (int j = 0; j < 4; ++j)
                vv[mi][ni][j] = fmaxf((float)acc[mi][ni][j], 0.0f);

    // ---- stage relu(C) into Ot ----
#pragma unroll
    for (int mi = 0; mi < 2; ++mi)
#pragma unroll
        for (int ni = 0; ni < 2; ++ni)
#pragma unroll
            for (int j = 0; j < 4; ++j)
                Ot[wr + mi * 16 + fq * 4 + j][wc + ni * 16 + fr] = (bf16)vv[mi][ni][j];
    __syncthreads();
    int er = tid >> 2, ec = (tid & 3) * 16;
    size_t gbase = ((size_t)h * T + row0 + er) * NN + col0 + ec;
    bf16x8 o0 = *(bf16x8*)&Ot[er][ec];
    bf16x8 o1 = *(bf16x8*)&Ot[er][ec + 8];

    if (MODE == 0) {
        *(bf16x8*)(xs + gbase) = o0;
        *(bf16x8*)(xs + gbase + 8) = o1;
        __syncthreads();   // all LDS reads done; reuse Ot for qr
#pragma unroll
        for (int mi = 0; mi < 2; ++mi)
#pragma unroll
            for (int ni = 0; ni < 2; ++ni)
#pragma unroll
                for (int j = 0; j < 4; ++j) {
                    float v = vv[mi][ni][j];
                    float p = __shfl_xor(v, 1, 64);           // partner col n^1
                    int m = row0 + wr + mi * 16 + fq * 4 + j;
                    int n = col0 + wc + ni * 16 + fr;
                    float cs = (float)cosH[(size_t)m * (NN / 2) + (n >> 1)];
                    float sn = (float)sinH[(size_t)m * (NN / 2) + (n >> 1)];
                    float qv = v * cs + ((n & 1) ? p * sn : -p * sn);
                    Ot[wr + mi * 16 + fq * 4 + j][wc + ni * 16 + fr] = (bf16)qv;
                }
        __syncthreads();
        bf16x8 q0 = *(bf16x8*)&Ot[er][ec];
        bf16x8 q1 = *(bf16x8*)&Ot[er][ec + 8];
        *(bf16x8*)(qr + gbase) = q0;
        *(bf16x8*)(qr + gbase + 8) = q1;
    } else {
        bf16x8 x0 = *(const bf16x8*)(xs + gbase);
        bf16x8 x1 = *(const bf16x8*)(xs + gbase + 8);
        bf16x8 r0v, r1v;
#pragma unroll
        for (int k = 0; k < 8; ++k) {
            r0v[k] = (bf16)((float)o0[k] * (float)x0[k]);
            r1v[k] = (bf16)((float)o1[k] * (float)x1[k]);
        }
        *(bf16x8*)(xs + gbase) = r0v;
        *(bf16x8*)(xs + gbase + 8) = r1v;
    }
}

// ---------------- scores GEMM: spart[ks][h][t][s] (lower-tri 64-tiles) ------
__global__ __launch_bounds__(256) void qq_mfma_k(const bf16* __restrict__ qrb,
                                                 float* __restrict__ spart) {
    __shared__ __align__(16) char smem[10240];
    bf16 (*As)[40] = (bf16(*)[40])smem;
    bf16 (*Bs)[40] = (bf16(*)[40])(smem + 5120);
    int p = blockIdx.x;            // 0..35 -> (ti,tj), tj<=ti
    int ti = 0, accu = 0;
    while (accu + ti + 1 <= p) { ++ti; accu += ti; }
    int tj = p - accu;
    int h = blockIdx.y, ksplit = blockIdx.z;
    const bf16* Q = qrb + (size_t)h * T * NN + (size_t)ksplit * (NN / QKS);
    const bf16* Ap = Q + (size_t)(ti * 64) * NN;
    const bf16* Bp = Q + (size_t)(tj * 64) * NN;
    int tid = threadIdx.x;
    f32x4 acc[2][2];
#pragma unroll
    for (int i = 0; i < 2; ++i)
#pragma unroll
        for (int j = 0; j < 2; ++j) acc[i][j] = f32x4{0.f, 0.f, 0.f, 0.f};
    gemm_core64(Ap, NN, Bp, NN, (NN / QKS) / 32, As, Bs, acc, tid);

    int lane = tid & 63, wid = tid >> 6;
    int wr = (wid >> 1) * 32, wc = (wid & 1) * 32;
    int fr = lane & 15, fq = lane >> 4;
    float* outp = spart + (size_t)(ksplit * H + h) * T * T;
#pragma unroll
    for (int mi = 0; mi < 2; ++mi)
#pragma unroll
        for (int ni = 0; ni < 2; ++ni) {
            int s = tj * 64 + wc + ni * 16 + fr;
            int mbase = ti * 64 + wr + mi * 16 + fq * 4;
#pragma unroll
            for (int j = 0; j < 4; ++j)
                outp[(size_t)(mbase + j) * T + s] = acc[mi][ni][j];
        }
}

// ---------------- sb[h][t][s] = bf16(sum_ks spart), strict causal mask ------
__global__ __launch_bounds__(256) void mask_cvt_k(const float* __restrict__ spart,
                                                  bf16* __restrict__ sb) {
    int t = blockIdx.x * 2 + (threadIdx.x >> 7);
    int h = blockIdx.y;
    int l = threadIdx.x & 127;
    int s = l * 4;
    const float* s0 = spart + ((size_t)h * T + t) * T + s;
    const size_t st = (size_t)H * T * T;
    float4 w0 = *(const float4*)(s0);
    float4 w1 = *(const float4*)(s0 + st);
    float4 w2 = *(const float4*)(s0 + 2 * st);
    float4 w3 = *(const float4*)(s0 + 3 * st);
    bf16x4 o;
    o[0] = (bf16)((s + 0 < t) ? (w0.x + w1.x + w2.x + w3.x) : 0.0f);
    o[1] = (bf16)((s + 1 < t) ? (w0.y + w1.y + w2.y + w3.y) : 0.0f);
    o[2] = (bf16)((s + 2 < t) ? (w0.z + w1.z + w2.z + w3.z) : 0.0f);
    o[3] = (bf16)((s + 3 < t) ? (w0.w + w1.w + w2.w + w3.w) : 0.0f);
    *(bf16x4*)(sb + ((size_t)h * T + t) * T + s) = o;
}

// ---------------- av: ykv_pre[h][t][d] = sum_s sb[t,s] * x[s,d] (MFMA) ------
__global__ __launch_bounds__(256) void av_mfma_k(const bf16* __restrict__ sb,
                                                 const bf16* __restrict__ xbT,
                                                 float* __restrict__ ykv_pre) {
    __shared__ __align__(16) char smem[10240];
    bf16 (*As)[40] = (bf16(*)[40])smem;
    bf16 (*Bs)[40] = (bf16(*)[40])(smem + 5120);
    int h = blockIdx.z;
    int ti = blockIdx.y;
    int row0 = ti * 64, col0 = blockIdx.x * 64;
    const bf16* Ap = sb + ((size_t)h * T + row0) * T;
    const bf16* Bp = xbT + (size_t)col0 * T;
    int tid = threadIdx.x;
    f32x4 acc[2][2];
#pragma unroll
    for (int i = 0; i < 2; ++i)
#pragma unroll
        for (int j = 0; j < 2; ++j) acc[i][j] = f32x4{0.f, 0.f, 0.f, 0.f};
    // causal: sb[t][s]==0 for s>=t, so only need k < (ti+1)*64
    gemm_core64(Ap, T, Bp, T, (ti + 1) * 2, As, Bs, acc, tid);

    int lane = tid & 63, wid = tid >> 6;
    int wr = (wid >> 1) * 32, wc = (wid & 1) * 32;
    int fr = lane & 15, fq = lane >> 4;
#pragma unroll
    for (int mi = 0; mi < 2; ++mi)
#pragma unroll
        for (int ni = 0; ni < 2; ++ni) {
            int n = col0 + wc + ni * 16 + fr;
            int mbase = row0 + wr + mi * 16 + fq * 4;
#pragma unroll
            for (int j = 0; j < 4; ++j)
                ykv_pre[((size_t)h * T + (mbase + j)) * D + n] = acc[mi][ni][j];
        }
}

// ---------------- ykv LN: ykvb = LN(ykv_pre) --------------------------------
__global__ __launch_bounds__(256) void ykv_ln_k(const float* __restrict__ ykv_pre,
                                                bf16* __restrict__ ykvb) {
    __shared__ float red[4];
    int t = blockIdx.x, h = blockIdx.y, d = threadIdx.x;
    float a = ykv_pre[((size_t)h * T + t) * D + d];
    float m = blk_sum256(a, red) * (1.0f / D);
    float df = a - m;
    float vv = blk_sum256(df * df, red) * (1.0f / D);
    ykvb[((size_t)h * T + t) * D + d] = (bf16)(df * rsqrtf(vv + EPSF));
}

// ---------------- decoder GEMM (split-K, 64x64 tiles) -----------------------
__global__ __launch_bounds__(256) void dec_mfma_k(const bf16* __restrict__ xyb,
                                                  const bf16* __restrict__ decT,
                                                  float* __restrict__ ypart) {
    __shared__ __align__(16) char smem[10240];
    bf16 (*As)[40] = (bf16(*)[40])smem;
    bf16 (*Bs)[40] = (bf16(*)[40])(smem + 5120);
    int ks = blockIdx.z;
    int cbeg = ks * ((H * NN) / DSPLIT);   // 1024-wide slices, within one head
    int h = cbeg >> 13, n0 = cbeg & (NN - 1);
    int row0 = blockIdx.y * 64, col0 = blockIdx.x * 64;
    const bf16* Ap = xyb + ((size_t)h * T + row0) * NN + n0;
    const bf16* Bp = decT + (size_t)col0 * (H * NN) + cbeg;
    int tid = threadIdx.x;
    f32x4 acc[2][2];
#pragma unroll
    for (int i = 0; i < 2; ++i)
#pragma unroll
        for (int j = 0; j < 2; ++j) acc[i][j] = f32x4{0.f, 0.f, 0.f, 0.f};
    gemm_core64(Ap, NN, Bp, H * NN, (H * NN / DSPLIT) / 32, As, Bs, acc, tid);

    int lane = tid & 63, wid = tid >> 6;
    int wr = (wid >> 1) * 32, wc = (wid & 1) * 32;
    int fr = lane & 15, fq = lane >> 4;
#pragma unroll
    for (int mi = 0; mi < 2; ++mi)
#pragma unroll
        for (int ni = 0; ni < 2; ++ni) {
            int n = col0 + wc + ni * 16 + fr;
            int mbase = row0 + wr + mi * 16 + fq * 4;
#pragma unroll
            for (int j = 0; j < 4; ++j)
                ypart[((size_t)ks * T + (mbase + j)) * D + n] = acc[mi][ni][j];
        }
}

// ---------------- y = LN(sum ypart); x = LN(x + y); bf16 + bf16^T copies ----
__global__ __launch_bounds__(256) void final_ln_k(const float* __restrict__ ypart,
                                                  float* __restrict__ x,
                                                  bf16* __restrict__ xb,
                                                  bf16* __restrict__ xbT) {
    __shared__ float red[4];
    int t = blockIdx.x, d = threadIdx.x;
    float ys = 0.0f;
#pragma unroll
    for (int ks = 0; ks < DSPLIT; ++ks) ys += ypart[((size_t)ks * T + t) * D + d];
    float m = blk_sum256(ys, red) * (1.0f / D);
    float df = ys - m;
    float vv = blk_sum256(df * df, red) * (1.0f / D);
    float yln = df * rsqrtf(vv + EPSF);
    float val = x[(size_t)t * D + d] + yln;
    float m2 = blk_sum256(val, red) * (1.0f / D);
    float df2 = val - m2;
    float v2 = blk_sum256(df2 * df2, red) * (1.0f / D);
    float r = df2 * rsqrtf(v2 + EPSF);
    x[(size_t)t * D + d] = r;
    xb[(size_t)t * D + d] = (bf16)r;
    xbT[(size_t)d * T + t] = (bf16)r;
}

// ---------------- logits = x @ lm_head (f32) --------------------------------
__global__ __launch_bounds__(256) void logits_k(const float* __restrict__ x,
                                                const float* __restrict__ lm,
                                                float* __restrict__ out) {
    int t = blockIdx.x, v = threadIdx.x;
    float a = 0.0f;
    for (int d = 0; d < D; ++d)
        a = fmaf(x[(size_t)t * D + d], lm[(size_t)d * V + v], a);
    out[(size_t)t * V + v] = a;
}

extern "C" void kernel_launch(void* const* d_in, const int* in_sizes, int n_in,
                              void* d_out, int out_size, void* d_ws, size_t ws_size,
                              hipStream_t stream) {
    const int*   idx       = (const int*)d_in[0];
    const float* embed     = (const float*)d_in[1];
    const float* encoder   = (const float*)d_in[2];
    const float* encoder_v = (const float*)d_in[3];
    const float* decoder   = (const float*)d_in[4];
    const float* lm_head   = (const float*)d_in[5];
    float* out = (float*)d_out;

    // ---- workspace layout (~146 MB) ----
    char* W = (char*)d_ws;
    float* x       = (float*)W; W += (size_t)T * D * 4;
    float* scratch = (float*)W; W += (size_t)QKS * H * T * T * 4;  // spart / ykv_pre / ypart union
    bf16* xb    = (bf16*)W; W += (size_t)T * D * 2;
    bf16* xbT   = (bf16*)W; W += (size_t)D * T * 2;
    bf16* sb    = (bf16*)W; W += (size_t)H * T * T * 2;
    bf16* ykvb  = (bf16*)W; W += (size_t)H * T * D * 2;
    bf16* encT  = (bf16*)W; W += (size_t)H * NN * D * 2;
    bf16* encVT = (bf16*)W; W += (size_t)H * NN * D * 2;
    bf16* decT  = (bf16*)W; W += (size_t)D * H * NN * 2;
    bf16* cosH  = (bf16*)W; W += (size_t)T * (NN / 2) * 2;
    bf16* sinH  = (bf16*)W; W += (size_t)T * (NN / 2) * 2;
    bf16* xs    = (bf16*)W; W += (size_t)H * T * NN * 2;
    bf16* qr    = (bf16*)W; W += (size_t)H * T * NN * 2;

    // ---- one-time per launch: weight transpose+convert, RoPE tables ----
    tcvt_k<<<dim3(NN / 32, D / 32, H), 256, 0, stream>>>(encoder, encT, D, NN);
    tcvt_k<<<dim3(NN / 32, D / 32, H), 256, 0, stream>>>(encoder_v, encVT, D, NN);
    tcvt_k<<<dim3(D / 32, (H * NN) / 32, 1), 256, 0, stream>>>(decoder, decT, H * NN, D);
    rope_tab_k<<<dim3((NN / 2) / 256, T), 256, 0, stream>>>(cosH, sinH);

    embed_ln_k<<<T, 256, 0, stream>>>(idx, embed, x, xb, xbT);

    for (int layer = 0; layer < N_LAYER; ++layer) {
        enc_mfma_k<0><<<dim3(NN / 64, T / 64, H), 256, 0, stream>>>(
            xb, encT, xs, qr, cosH, sinH, 0);
        qq_mfma_k<<<dim3(36, H, QKS), 256, 0, stream>>>(qr, scratch);
        mask_cvt_k<<<dim3(T / 2, H), 256, 0, stream>>>(scratch, sb);
        av_mfma_k<<<dim3(D / 64, T / 64, H), 256, 0, stream>>>(sb, xbT, scratch);
        ykv_ln_k<<<dim3(T, H), 256, 0, stream>>>(scratch, ykvb);
        enc_mfma_k<1><<<dim3(NN / 64, T / 64, H), 256, 0, stream>>>(
            ykvb, encVT, xs, nullptr, nullptr, nullptr, T * D);
        dec_mfma_k<<<dim3(D / 64, T / 64, DSPLIT), 256, 0, stream>>>(
            xs, decT, scratch);
        final_ln_k<<<T, 256, 0, stream>>>(scratch, x, xb, xbT);
    }

    logits_k<<<T, 256, 0, stream>>>(x, lm_head, out);
}

// Round 6
// 775.268 us; speedup vs baseline: 1.3852x; 1.2357x over previous
//
#include <hip/hip_runtime.h>
#include <hip/hip_bf16.h>

#define T   512
#define D   256
#define H   4
#define NN  8192
#define V   256
#define EPSF 1e-5f
#define QKS 4          // split-K for scores GEMM
#define DSPLIT 32      // split-K for decoder GEMM
#define N_LAYER 6

typedef __bf16 bf16;
typedef __attribute__((__ext_vector_type__(8))) __bf16 bf16x8;
typedef __attribute__((__ext_vector_type__(4))) __bf16 bf16x4;
typedef __attribute__((__ext_vector_type__(4))) float  f32x4;

#define MFMA16(a, b, c) __builtin_amdgcn_mfma_f32_16x16x32_bf16((a), (b), (c), 0, 0, 0)
// async global->LDS, 16B per lane; LDS dest is wave-uniform base + lane*16
#define GLD16(g, l)                                                         \
    __builtin_amdgcn_global_load_lds(                                       \
        (const __attribute__((address_space(1))) void*)(g),                 \
        (__attribute__((address_space(3))) void*)(l), 16, 0, 0)

// ---------------- block-wide sum over 256 threads ---------------------------
__device__ __forceinline__ float blk_sum256(float v, float* red) {
#pragma unroll
    for (int off = 32; off > 0; off >>= 1) v += __shfl_down(v, off, 64);
    int lane = threadIdx.x & 63, w = threadIdx.x >> 6;
    __syncthreads();
    if (lane == 0) red[w] = v;
    __syncthreads();
    return red[0] + red[1] + red[2] + red[3];
}

// ---------------- transpose + f32->bf16 convert (32x32 tiles) ---------------
__global__ __launch_bounds__(256) void tcvt_k(const float* __restrict__ in,
                                              bf16* __restrict__ out, int R, int C) {
    __shared__ float t[32][33];
    size_t hoff = (size_t)blockIdx.z * R * C;
    int c0 = blockIdx.x * 32, r0 = blockIdx.y * 32;
    int x = threadIdx.x & 31, y = threadIdx.x >> 5;
#pragma unroll
    for (int p = 0; p < 4; ++p)
        t[y + 8 * p][x] = in[hoff + (size_t)(r0 + y + 8 * p) * C + c0 + x];
    __syncthreads();
#pragma unroll
    for (int p = 0; p < 4; ++p)
        out[hoff + (size_t)(c0 + y + 8 * p) * R + r0 + x] = (bf16)t[x][y + 8 * p];
}

// ---------------- RoPE cos/sin HALF tables (pairs share angle) --------------
__global__ __launch_bounds__(256) void rope_tab_k(bf16* __restrict__ cosH,
                                                  bf16* __restrict__ sinH) {
    int k = blockIdx.x * 256 + threadIdx.x;     // 0..NN/2-1
    int t = blockIdx.y;
    float q = (float)(2 * k);
    float f = exp2f(q * (-16.0f / (float)NN)) * 0.15915494309189535f;
    float u = fmodf((float)t * f, 1.0f);
    float a = u * 6.283185307179586f;
    cosH[(size_t)t * (NN / 2) + k] = (bf16)cosf(a);
    sinH[(size_t)t * (NN / 2) + k] = (bf16)sinf(a);
}

// ---------------- x = LN(embed[idx]) (writes f32 + bf16 + bf16^T) -----------
__global__ __launch_bounds__(256) void embed_ln_k(const int* __restrict__ idx,
                                                  const float* __restrict__ embed,
                                                  float* __restrict__ x,
                                                  bf16* __restrict__ xb,
                                                  bf16* __restrict__ xbT) {
    __shared__ float red[4];
    int t = blockIdx.x, d = threadIdx.x;
    float e = embed[(size_t)idx[t] * D + d];
    float m = blk_sum256(e, red) * (1.0f / D);
    float df = e - m;
    float vv = blk_sum256(df * df, red) * (1.0f / D);
    float r = df * rsqrtf(vv + EPSF);
    x[(size_t)t * D + d] = r;
    xb[(size_t)t * D + d] = (bf16)r;
    xbT[(size_t)d * T + t] = (bf16)r;
}

// ---------------- MFMA 64x64 core: global_load_lds staging ------------------
// A row-major [m][k] (lda), B as rows of B^T [n][k] (ldb); BK=32.
// LDS linear [64][32] bf16 per operand (4KB), 16B-slot XOR swizzle:
//   LDS(row, slot') holds global (row, slot' ^ ((row>>1)&3)); each wave
//   stages 16 rows (1KB) per operand per kstep via one global_load_lds x16.
__device__ __forceinline__ void gemm_core64(const bf16* __restrict__ Ap, size_t lda,
                                            const bf16* __restrict__ Bp, size_t ldb,
                                            int ksteps, bf16* As, bf16* Bs,
                                            f32x4 acc[2][2], int tid) {
    int lane = tid & 63, wid = tid >> 6;
    int wr = (wid >> 1) * 32, wc = (wid & 1) * 32;
    int fr = lane & 15;
    int s  = lane >> 4;                        // k-slot 0..3 (8 bf16 each)
    // staging: wave w covers rows 16w..16w+15; lane l -> row 16w+l/4, slot l&3
    int srow  = wid * 16 + (lane >> 2);
    int sslot = (lane & 3) ^ ((srow >> 1) & 3);   // inverse-swizzled source
    const bf16* ag = Ap + (size_t)srow * lda + sslot * 8;
    const bf16* bg = Bp + (size_t)srow * ldb + sslot * 8;
    bf16* al = As + wid * 512;                 // wave-uniform LDS dest (1KB)
    bf16* bl = Bs + wid * 512;
    // fragment LDS byte offsets (swizzled read)
    int ar0 = wr + fr, ar1 = wr + 16 + fr;
    int br0 = wc + fr, br1 = wc + 16 + fr;
    const char* cA = (const char*)As;
    const char* cB = (const char*)Bs;
    int aoff0 = ar0 * 64 + ((s ^ ((ar0 >> 1) & 3)) << 4);
    int aoff1 = ar1 * 64 + ((s ^ ((ar1 >> 1) & 3)) << 4);
    int boff0 = br0 * 64 + ((s ^ ((br0 >> 1) & 3)) << 4);
    int boff1 = br1 * 64 + ((s ^ ((br1 >> 1) & 3)) << 4);
    for (int ks = 0; ks < ksteps; ++ks) {
        GLD16(ag + ks * 32, al);
        GLD16(bg + ks * 32, bl);
        __syncthreads();                       // drains vmcnt before reads
        bf16x8 a0 = *(const bf16x8*)(cA + aoff0);
        bf16x8 a1 = *(const bf16x8*)(cA + aoff1);
        bf16x8 b0 = *(const bf16x8*)(cB + boff0);
        bf16x8 b1 = *(const bf16x8*)(cB + boff1);
        acc[0][0] = MFMA16(a0, b0, acc[0][0]);
        acc[0][1] = MFMA16(a0, b1, acc[0][1]);
        acc[1][0] = MFMA16(a1, b0, acc[1][0]);
        acc[1][1] = MFMA16(a1, b1, acc[1][1]);
        __syncthreads();                       // WAR before next stage
    }
}

// ---------------- encoder GEMM + relu (+RoPE / *old), coalesced epilogue ----
// MODE 0: xs = relu(C); qr = rope(xs).  MODE 1: xs *= relu(C)  (xy in place)
template <int MODE>
__global__ __launch_bounds__(256) void enc_mfma_k(const bf16* __restrict__ A,
                                                  const bf16* __restrict__ Wt,
                                                  bf16* __restrict__ xs,
                                                  bf16* __restrict__ qr,
                                                  const bf16* __restrict__ cosH,
                                                  const bf16* __restrict__ sinH,
                                                  int aHeadStride) {
    __shared__ __align__(16) char smem[10240];
    bf16* As = (bf16*)smem;                       // 4096 B
    bf16* Bs = (bf16*)(smem + 4096);              // 4096 B
    bf16 (*Ot)[76] = (bf16(*)[76])smem;           // epilogue reuse, 9728 B
    int h = blockIdx.z;
    int row0 = blockIdx.y * 64, col0 = blockIdx.x * 64;
    const bf16* Ap = A + (size_t)h * aHeadStride + (size_t)row0 * D;
    const bf16* Bp = Wt + ((size_t)h * NN + col0) * D;
    int tid = threadIdx.x;
    f32x4 acc[2][2];
#pragma unroll
    for (int i = 0; i < 2; ++i)
#pragma unroll
        for (int j = 0; j < 2; ++j) acc[i][j] = f32x4{0.f, 0.f, 0.f, 0.f};
    gemm_core64(Ap, D, Bp, D, D / 32, As, Bs, acc, tid);
    // core ends with __syncthreads(): LDS free for reuse

    int lane = tid & 63, wid = tid >> 6;
    int wr = (wid >> 1) * 32, wc = (wid & 1) * 32;
    int fr = lane & 15, fq = lane >> 4;
    float vv[2][2][4];
#pragma unroll
    for (int mi = 0; mi < 2; ++mi)
#pragma unroll
        for (int ni = 0; ni < 2; ++ni)
#pragma unroll
            for (int j = 0; j < 4; ++j)
                vv[mi][ni][j] = fmaxf((float)acc[mi][ni][j], 0.0f);

    // ---- stage relu(C) into Ot ----
#pragma unroll
    for (int mi = 0; mi < 2; ++mi)
#pragma unroll
        for (int ni = 0; ni < 2; ++ni)
#pragma unroll
            for (int j = 0; j < 4; ++j)
                Ot[wr + mi * 16 + fq * 4 + j][wc + ni * 16 + fr] = (bf16)vv[mi][ni][j];
    __syncthreads();
    int er = tid >> 2, ec = (tid & 3) * 16;
    size_t gbase = ((size_t)h * T + row0 + er) * NN + col0 + ec;
    bf16x8 o0 = *(bf16x8*)&Ot[er][ec];
    bf16x8 o1 = *(bf16x8*)&Ot[er][ec + 8];

    if (MODE == 0) {
        *(bf16x8*)(xs + gbase) = o0;
        *(bf16x8*)(xs + gbase + 8) = o1;
        __syncthreads();   // all LDS reads done; reuse Ot for qr
#pragma unroll
        for (int mi = 0; mi < 2; ++mi)
#pragma unroll
            for (int ni = 0; ni < 2; ++ni)
#pragma unroll
                for (int j = 0; j < 4; ++j) {
                    float v = vv[mi][ni][j];
                    float p = __shfl_xor(v, 1, 64);           // partner col n^1
                    int m = row0 + wr + mi * 16 + fq * 4 + j;
                    int n = col0 + wc + ni * 16 + fr;
                    float cs = (float)cosH[(size_t)m * (NN / 2) + (n >> 1)];
                    float sn = (float)sinH[(size_t)m * (NN / 2) + (n >> 1)];
                    float qv = v * cs + ((n & 1) ? p * sn : -p * sn);
                    Ot[wr + mi * 16 + fq * 4 + j][wc + ni * 16 + fr] = (bf16)qv;
                }
        __syncthreads();
        bf16x8 q0 = *(bf16x8*)&Ot[er][ec];
        bf16x8 q1 = *(bf16x8*)&Ot[er][ec + 8];
        *(bf16x8*)(qr + gbase) = q0;
        *(bf16x8*)(qr + gbase + 8) = q1;
    } else {
        bf16x8 x0 = *(const bf16x8*)(xs + gbase);
        bf16x8 x1 = *(const bf16x8*)(xs + gbase + 8);
        bf16x8 r0v, r1v;
#pragma unroll
        for (int k = 0; k < 8; ++k) {
            r0v[k] = (bf16)((float)o0[k] * (float)x0[k]);
            r1v[k] = (bf16)((float)o1[k] * (float)x1[k]);
        }
        *(bf16x8*)(xs + gbase) = r0v;
        *(bf16x8*)(xs + gbase + 8) = r1v;
    }
}

// ---------------- scores GEMM: spart[ks][h][t][s] (lower-tri 64-tiles) ------
// 1-D grid, 576 blocks: bid%16 = (h,ksplit) group -> XCD = bid%8 pins each
// group's 2MB panel set to one XCD's L2.
__global__ __launch_bounds__(256) void qq_mfma_k(const bf16* __restrict__ qrb,
                                                 float* __restrict__ spart) {
    __shared__ __align__(16) char smem[8192];
    bf16* As = (bf16*)smem;
    bf16* Bs = (bf16*)(smem + 4096);
    int g = blockIdx.x & 15;          // (h, ksplit) group
    int h = g >> 2, ksplit = g & 3;
    int p = blockIdx.x >> 4;          // 0..35 -> (ti,tj), tj<=ti
    int ti = 0, accu = 0;
    while (accu + ti + 1 <= p) { ++ti; accu += ti; }
    int tj = p - accu;
    const bf16* Q = qrb + (size_t)h * T * NN + (size_t)ksplit * (NN / QKS);
    const bf16* Ap = Q + (size_t)(ti * 64) * NN;
    const bf16* Bp = Q + (size_t)(tj * 64) * NN;
    int tid = threadIdx.x;
    f32x4 acc[2][2];
#pragma unroll
    for (int i = 0; i < 2; ++i)
#pragma unroll
        for (int j = 0; j < 2; ++j) acc[i][j] = f32x4{0.f, 0.f, 0.f, 0.f};
    gemm_core64(Ap, NN, Bp, NN, (NN / QKS) / 32, As, Bs, acc, tid);

    int lane = tid & 63, wid = tid >> 6;
    int wr = (wid >> 1) * 32, wc = (wid & 1) * 32;
    int fr = lane & 15, fq = lane >> 4;
    float* outp = spart + (size_t)(ksplit * H + h) * T * T;
#pragma unroll
    for (int mi = 0; mi < 2; ++mi)
#pragma unroll
        for (int ni = 0; ni < 2; ++ni) {
            int s = tj * 64 + wc + ni * 16 + fr;
            int mbase = ti * 64 + wr + mi * 16 + fq * 4;
#pragma unroll
            for (int j = 0; j < 4; ++j)
                outp[(size_t)(mbase + j) * T + s] = acc[mi][ni][j];
        }
}

// ---------------- sb[h][t][s] = bf16(sum_ks spart), strict causal mask ------
__global__ __launch_bounds__(256) void mask_cvt_k(const float* __restrict__ spart,
                                                  bf16* __restrict__ sb) {
    int t = blockIdx.x * 2 + (threadIdx.x >> 7);
    int h = blockIdx.y;
    int l = threadIdx.x & 127;
    int s = l * 4;
    const float* s0 = spart + ((size_t)h * T + t) * T + s;
    const size_t st = (size_t)H * T * T;
    float4 w0 = *(const float4*)(s0);
    float4 w1 = *(const float4*)(s0 + st);
    float4 w2 = *(const float4*)(s0 + 2 * st);
    float4 w3 = *(const float4*)(s0 + 3 * st);
    bf16x4 o;
    o[0] = (bf16)((s + 0 < t) ? (w0.x + w1.x + w2.x + w3.x) : 0.0f);
    o[1] = (bf16)((s + 1 < t) ? (w0.y + w1.y + w2.y + w3.y) : 0.0f);
    o[2] = (bf16)((s + 2 < t) ? (w0.z + w1.z + w2.z + w3.z) : 0.0f);
    o[3] = (bf16)((s + 3 < t) ? (w0.w + w1.w + w2.w + w3.w) : 0.0f);
    *(bf16x4*)(sb + ((size_t)h * T + t) * T + s) = o;
}

// ---------------- av: ykv_pre[h][t][d] = sum_s sb[t,s] * x[s,d] (MFMA) ------
__global__ __launch_bounds__(256) void av_mfma_k(const bf16* __restrict__ sb,
                                                 const bf16* __restrict__ xbT,
                                                 float* __restrict__ ykv_pre) {
    __shared__ __align__(16) char smem[8192];
    bf16* As = (bf16*)smem;
    bf16* Bs = (bf16*)(smem + 4096);
    int h = blockIdx.z;
    int ti = blockIdx.y;
    int row0 = ti * 64, col0 = blockIdx.x * 64;
    const bf16* Ap = sb + ((size_t)h * T + row0) * T;
    const bf16* Bp = xbT + (size_t)col0 * T;
    int tid = threadIdx.x;
    f32x4 acc[2][2];
#pragma unroll
    for (int i = 0; i < 2; ++i)
#pragma unroll
        for (int j = 0; j < 2; ++j) acc[i][j] = f32x4{0.f, 0.f, 0.f, 0.f};
    // causal: sb[t][s]==0 for s>=t, so only need k < (ti+1)*64
    gemm_core64(Ap, T, Bp, T, (ti + 1) * 2, As, Bs, acc, tid);

    int lane = tid & 63, wid = tid >> 6;
    int wr = (wid >> 1) * 32, wc = (wid & 1) * 32;
    int fr = lane & 15, fq = lane >> 4;
#pragma unroll
    for (int mi = 0; mi < 2; ++mi)
#pragma unroll
        for (int ni = 0; ni < 2; ++ni) {
            int n = col0 + wc + ni * 16 + fr;
            int mbase = row0 + wr + mi * 16 + fq * 4;
#pragma unroll
            for (int j = 0; j < 4; ++j)
                ykv_pre[((size_t)h * T + (mbase + j)) * D + n] = acc[mi][ni][j];
        }
}

// ---------------- ykv LN: ykvb = LN(ykv_pre) --------------------------------
__global__ __launch_bounds__(256) void ykv_ln_k(const float* __restrict__ ykv_pre,
                                                bf16* __restrict__ ykvb) {
    __shared__ float red[4];
    int t = blockIdx.x, h = blockIdx.y, d = threadIdx.x;
    float a = ykv_pre[((size_t)h * T + t) * D + d];
    float m = blk_sum256(a, red) * (1.0f / D);
    float df = a - m;
    float vv = blk_sum256(df * df, red) * (1.0f / D);
    ykvb[((size_t)h * T + t) * D + d] = (bf16)(df * rsqrtf(vv + EPSF));
}

// ---------------- decoder GEMM (split-K, 64x64 tiles, XCD-pinned slices) ----
// 1-D grid, 1024 blocks: ks = bid%32 -> XCD = ks%8
__global__ __launch_bounds__(256) void dec_mfma_k(const bf16* __restrict__ xyb,
                                                  const bf16* __restrict__ decT,
                                                  float* __restrict__ ypart) {
    __shared__ __align__(16) char smem[8192];
    bf16* As = (bf16*)smem;
    bf16* Bs = (bf16*)(smem + 4096);
    int ks = blockIdx.x & 31;
    int t  = blockIdx.x >> 5;          // 0..31: col = t&3, row = t>>2
    int col0 = (t & 3) * 64, row0 = (t >> 2) * 64;
    int cbeg = ks * ((H * NN) / DSPLIT);   // 1024-wide slices, within one head
    int h = cbeg >> 13, n0 = cbeg & (NN - 1);
    const bf16* Ap = xyb + ((size_t)h * T + row0) * NN + n0;
    const bf16* Bp = decT + (size_t)col0 * (H * NN) + cbeg;
    int tid = threadIdx.x;
    f32x4 acc[2][2];
#pragma unroll
    for (int i = 0; i < 2; ++i)
#pragma unroll
        for (int j = 0; j < 2; ++j) acc[i][j] = f32x4{0.f, 0.f, 0.f, 0.f};
    gemm_core64(Ap, NN, Bp, H * NN, (H * NN / DSPLIT) / 32, As, Bs, acc, tid);

    int lane = tid & 63, wid = tid >> 6;
    int wr = (wid >> 1) * 32, wc = (wid & 1) * 32;
    int fr = lane & 15, fq = lane >> 4;
#pragma unroll
    for (int mi = 0; mi < 2; ++mi)
#pragma unroll
        for (int ni = 0; ni < 2; ++ni) {
            int n = col0 + wc + ni * 16 + fr;
            int mbase = row0 + wr + mi * 16 + fq * 4;
#pragma unroll
            for (int j = 0; j < 4; ++j)
                ypart[((size_t)ks * T + (mbase + j)) * D + n] = acc[mi][ni][j];
        }
}

// ---------------- y = LN(sum ypart); x = LN(x + y); bf16 + bf16^T copies ----
__global__ __launch_bounds__(256) void final_ln_k(const float* __restrict__ ypart,
                                                  float* __restrict__ x,
                                                  bf16* __restrict__ xb,
                                                  bf16* __restrict__ xbT) {
    __shared__ float red[4];
    int t = blockIdx.x, d = threadIdx.x;
    float ys = 0.0f;
#pragma unroll
    for (int ks = 0; ks < DSPLIT; ++ks) ys += ypart[((size_t)ks * T + t) * D + d];
    float m = blk_sum256(ys, red) * (1.0f / D);
    float df = ys - m;
    float vv = blk_sum256(df * df, red) * (1.0f / D);
    float yln = df * rsqrtf(vv + EPSF);
    float val = x[(size_t)t * D + d] + yln;
    float m2 = blk_sum256(val, red) * (1.0f / D);
    float df2 = val - m2;
    float v2 = blk_sum256(df2 * df2, red) * (1.0f / D);
    float r = df2 * rsqrtf(v2 + EPSF);
    x[(size_t)t * D + d] = r;
    xb[(size_t)t * D + d] = (bf16)r;
    xbT[(size_t)d * T + t] = (bf16)r;
}

// ---------------- logits = x @ lm_head (f32) --------------------------------
__global__ __launch_bounds__(256) void logits_k(const float* __restrict__ x,
                                                const float* __restrict__ lm,
                                                float* __restrict__ out) {
    int t = blockIdx.x, v = threadIdx.x;
    float a = 0.0f;
    for (int d = 0; d < D; ++d)
        a = fmaf(x[(size_t)t * D + d], lm[(size_t)d * V + v], a);
    out[(size_t)t * V + v] = a;
}

extern "C" void kernel_launch(void* const* d_in, const int* in_sizes, int n_in,
                              void* d_out, int out_size, void* d_ws, size_t ws_size,
                              hipStream_t stream) {
    const int*   idx       = (const int*)d_in[0];
    const float* embed     = (const float*)d_in[1];
    const float* encoder   = (const float*)d_in[2];
    const float* encoder_v = (const float*)d_in[3];
    const float* decoder   = (const float*)d_in[4];
    const float* lm_head   = (const float*)d_in[5];
    float* out = (float*)d_out;

    // ---- workspace layout (~146 MB) ----
    char* W = (char*)d_ws;
    float* x       = (float*)W; W += (size_t)T * D * 4;
    float* scratch = (float*)W; W += (size_t)QKS * H * T * T * 4;  // spart / ykv_pre / ypart union
    bf16* xb    = (bf16*)W; W += (size_t)T * D * 2;
    bf16* xbT   = (bf16*)W; W += (size_t)D * T * 2;
    bf16* sb    = (bf16*)W; W += (size_t)H * T * T * 2;
    bf16* ykvb  = (bf16*)W; W += (size_t)H * T * D * 2;
    bf16* encT  = (bf16*)W; W += (size_t)H * NN * D * 2;
    bf16* encVT = (bf16*)W; W += (size_t)H * NN * D * 2;
    bf16* decT  = (bf16*)W; W += (size_t)D * H * NN * 2;
    bf16* cosH  = (bf16*)W; W += (size_t)T * (NN / 2) * 2;
    bf16* sinH  = (bf16*)W; W += (size_t)T * (NN / 2) * 2;
    bf16* xs    = (bf16*)W; W += (size_t)H * T * NN * 2;
    bf16* qr    = (bf16*)W; W += (size_t)H * T * NN * 2;

    // ---- one-time per launch: weight transpose+convert, RoPE tables ----
    tcvt_k<<<dim3(NN / 32, D / 32, H), 256, 0, stream>>>(encoder, encT, D, NN);
    tcvt_k<<<dim3(NN / 32, D / 32, H), 256, 0, stream>>>(encoder_v, encVT, D, NN);
    tcvt_k<<<dim3(D / 32, (H * NN) / 32, 1), 256, 0, stream>>>(decoder, decT, H * NN, D);
    rope_tab_k<<<dim3((NN / 2) / 256, T), 256, 0, stream>>>(cosH, sinH);

    embed_ln_k<<<T, 256, 0, stream>>>(idx, embed, x, xb, xbT);

    for (int layer = 0; layer < N_LAYER; ++layer) {
        enc_mfma_k<0><<<dim3(NN / 64, T / 64, H), 256, 0, stream>>>(
            xb, encT, xs, qr, cosH, sinH, 0);
        qq_mfma_k<<<576, 256, 0, stream>>>(qr, scratch);
        mask_cvt_k<<<dim3(T / 2, H), 256, 0, stream>>>(scratch, sb);
        av_mfma_k<<<dim3(D / 64, T / 64, H), 256, 0, stream>>>(sb, xbT, scratch);
        ykv_ln_k<<<dim3(T, H), 256, 0, stream>>>(scratch, ykvb);
        enc_mfma_k<1><<<dim3(NN / 64, T / 64, H), 256, 0, stream>>>(
            ykvb, encVT, xs, nullptr, nullptr, nullptr, T * D);
        dec_mfma_k<<<1024, 256, 0, stream>>>(xs, decT, scratch);
        final_ln_k<<<T, 256, 0, stream>>>(scratch, x, xb, xbT);
    }

    logits_k<<<T, 256, 0, stream>>>(x, lm_head, out);
}

// Round 7
// 698.532 us; speedup vs baseline: 1.5374x; 1.1099x over previous
//
#include <hip/hip_runtime.h>
#include <hip/hip_bf16.h>

#define T   512
#define D   256
#define H   4
#define NN  8192
#define V   256
#define EPSF 1e-5f
#define QKS 4          // split-K for scores GEMM
#define DSPLIT 16      // split-K for decoder GEMM
#define N_LAYER 6

typedef __bf16 bf16;
typedef __attribute__((__ext_vector_type__(8))) __bf16 bf16x8;
typedef __attribute__((__ext_vector_type__(4))) __bf16 bf16x4;
typedef __attribute__((__ext_vector_type__(4))) float  f32x4;

#define MFMA16(a, b, c) __builtin_amdgcn_mfma_f32_16x16x32_bf16((a), (b), (c), 0, 0, 0)
// async global->LDS, 16B per lane; LDS dest is wave-uniform base + lane*16
#define GLD16(g, l)                                                         \
    __builtin_amdgcn_global_load_lds(                                       \
        (const __attribute__((address_space(1))) void*)(g),                 \
        (__attribute__((address_space(3))) void*)(l), 16, 0, 0)

// ---------------- block-wide sum over 256 threads ---------------------------
__device__ __forceinline__ float blk_sum256(float v, float* red) {
#pragma unroll
    for (int off = 32; off > 0; off >>= 1) v += __shfl_down(v, off, 64);
    int lane = threadIdx.x & 63, w = threadIdx.x >> 6;
    __syncthreads();
    if (lane == 0) red[w] = v;
    __syncthreads();
    return red[0] + red[1] + red[2] + red[3];
}

// ---------------- transpose + f32->bf16 convert (32x32 tiles) ---------------
__global__ __launch_bounds__(256) void tcvt_k(const float* __restrict__ in,
                                              bf16* __restrict__ out, int R, int C) {
    __shared__ float t[32][33];
    size_t hoff = (size_t)blockIdx.z * R * C;
    int c0 = blockIdx.x * 32, r0 = blockIdx.y * 32;
    int x = threadIdx.x & 31, y = threadIdx.x >> 5;
#pragma unroll
    for (int p = 0; p < 4; ++p)
        t[y + 8 * p][x] = in[hoff + (size_t)(r0 + y + 8 * p) * C + c0 + x];
    __syncthreads();
#pragma unroll
    for (int p = 0; p < 4; ++p)
        out[hoff + (size_t)(c0 + y + 8 * p) * R + r0 + x] = (bf16)t[x][y + 8 * p];
}

// ---------------- RoPE cos/sin HALF tables (pairs share angle) --------------
__global__ __launch_bounds__(256) void rope_tab_k(bf16* __restrict__ cosH,
                                                  bf16* __restrict__ sinH) {
    int k = blockIdx.x * 256 + threadIdx.x;     // 0..NN/2-1
    int t = blockIdx.y;
    float q = (float)(2 * k);
    float f = exp2f(q * (-16.0f / (float)NN)) * 0.15915494309189535f;
    float u = fmodf((float)t * f, 1.0f);
    float a = u * 6.283185307179586f;
    cosH[(size_t)t * (NN / 2) + k] = (bf16)cosf(a);
    sinH[(size_t)t * (NN / 2) + k] = (bf16)sinf(a);
}

// ---------------- x = LN(embed[idx]) (writes f32 + bf16 + bf16^T) -----------
__global__ __launch_bounds__(256) void embed_ln_k(const int* __restrict__ idx,
                                                  const float* __restrict__ embed,
                                                  float* __restrict__ x,
                                                  bf16* __restrict__ xb,
                                                  bf16* __restrict__ xbT) {
    __shared__ float red[4];
    int t = blockIdx.x, d = threadIdx.x;
    float e = embed[(size_t)idx[t] * D + d];
    float m = blk_sum256(e, red) * (1.0f / D);
    float df = e - m;
    float vv = blk_sum256(df * df, red) * (1.0f / D);
    float r = df * rsqrtf(vv + EPSF);
    x[(size_t)t * D + d] = r;
    xb[(size_t)t * D + d] = (bf16)r;
    xbT[(size_t)d * T + t] = (bf16)r;
}

// ---------------- MFMA 64x64 core v2: BK=64, 2-phase gload_lds pipeline -----
// A row-major [m][k] (lda), B as rows of B^T [n][k] (ldb).
// LDS: A0|A1|B0|B1, each [64 rows][64 k] bf16 (8KB), 32KB total.
// Swizzle: LDS(row, slot) = global(row, slot ^ (row&7)), slot = 16B unit.
// Per kstep: issue next-tile GLD16s -> ds_read+8xMFMA current -> 1 barrier.
__device__ __forceinline__ void gemm_core64(const bf16* __restrict__ Ap, size_t lda,
                                            const bf16* __restrict__ Bp, size_t ldb,
                                            int ksteps, bf16* lds,
                                            f32x4 acc[2][2], int tid) {
    int lane = tid & 63, wid = tid >> 6;
    int wr = (wid >> 1) * 32, wc = (wid & 1) * 32;
    int fr = lane & 15, s = lane >> 4;
    // staging: wave w covers rows 16w..16w+15 in 2 GLD rounds (8 rows each)
    int srow = wid * 16 + (lane >> 3);
    int sx   = ((lane & 7) ^ (srow & 7)) * 8;      // inverse-swizzled src elem
    const bf16* ag = Ap + (size_t)srow * lda + sx;
    const bf16* bg = Bp + (size_t)srow * ldb + sx;
    bf16* a_w = lds + wid * 1024;                  // wave-uniform dests
    bf16* b_w = lds + 8192 + wid * 1024;
    // fragment read byte-offsets (swizzled)
    int ar = wr + fr, br = wc + fr;
    int aoff0 = ar * 128 + (((s)     ^ (ar & 7)) << 4);   // kc=0
    int aoff1 = ar * 128 + (((4 + s) ^ (ar & 7)) << 4);   // kc=1
    int boff0 = br * 128 + (((s)     ^ (br & 7)) << 4);
    int boff1 = br * 128 + (((4 + s) ^ (br & 7)) << 4);
    // prologue: stage ks=0 into buffer 0
    GLD16(ag, a_w);  GLD16(ag + 8 * lda, a_w + 512);
    GLD16(bg, b_w);  GLD16(bg + 8 * ldb, b_w + 512);
    __syncthreads();
    for (int ks = 0; ks < ksteps; ++ks) {
        int cur = ks & 1;
        if (ks + 1 < ksteps) {                     // issue-early: overlap w/ MFMA
            int nxt = cur ^ 1;
            size_t ko = (size_t)(ks + 1) * 64;
            bf16* an = lds + nxt * 4096 + wid * 1024;
            bf16* bn = lds + 8192 + nxt * 4096 + wid * 1024;
            GLD16(ag + ko, an);  GLD16(ag + ko + 8 * lda, an + 512);
            GLD16(bg + ko, bn);  GLD16(bg + ko + 8 * ldb, bn + 512);
        }
        const char* cA = (const char*)(lds + cur * 4096);
        const char* cB = (const char*)(lds + 8192 + cur * 4096);
        bf16x8 a00 = *(const bf16x8*)(cA + aoff0);
        bf16x8 a01 = *(const bf16x8*)(cA + aoff1);
        bf16x8 a10 = *(const bf16x8*)(cA + aoff0 + 2048);  // row +16
        bf16x8 a11 = *(const bf16x8*)(cA + aoff1 + 2048);
        bf16x8 b00 = *(const bf16x8*)(cB + boff0);
        bf16x8 b01 = *(const bf16x8*)(cB + boff1);
        bf16x8 b10 = *(const bf16x8*)(cB + boff0 + 2048);
        bf16x8 b11 = *(const bf16x8*)(cB + boff1 + 2048);
        acc[0][0] = MFMA16(a00, b00, acc[0][0]);
        acc[0][0] = MFMA16(a01, b01, acc[0][0]);
        acc[0][1] = MFMA16(a00, b10, acc[0][1]);
        acc[0][1] = MFMA16(a01, b11, acc[0][1]);
        acc[1][0] = MFMA16(a10, b00, acc[1][0]);
        acc[1][0] = MFMA16(a11, b01, acc[1][0]);
        acc[1][1] = MFMA16(a10, b10, acc[1][1]);
        acc[1][1] = MFMA16(a11, b11, acc[1][1]);
        __syncthreads();   // drains next-tile vmcnt + WAR on cur buffer
    }
}

// ---------------- encoder GEMM + relu (+RoPE / *old), coalesced epilogue ----
// MODE 0: xs = relu(C); qr = rope(xs).  MODE 1: xs *= relu(C)  (xy in place)
template <int MODE>
__global__ __launch_bounds__(256) void enc_mfma_k(const bf16* __restrict__ A,
                                                  const bf16* __restrict__ Wt,
                                                  bf16* __restrict__ xs,
                                                  bf16* __restrict__ qr,
                                                  const bf16* __restrict__ cosH,
                                                  const bf16* __restrict__ sinH,
                                                  int aHeadStride) {
    __shared__ __align__(16) char smem[32768];
    bf16 (*Ot)[76] = (bf16(*)[76])smem;           // epilogue reuse, 9728 B
    int h = blockIdx.z;
    int row0 = blockIdx.y * 64, col0 = blockIdx.x * 64;
    const bf16* Ap = A + (size_t)h * aHeadStride + (size_t)row0 * D;
    const bf16* Bp = Wt + ((size_t)h * NN + col0) * D;
    int tid = threadIdx.x;
    f32x4 acc[2][2];
#pragma unroll
    for (int i = 0; i < 2; ++i)
#pragma unroll
        for (int j = 0; j < 2; ++j) acc[i][j] = f32x4{0.f, 0.f, 0.f, 0.f};
    gemm_core64(Ap, D, Bp, D, D / 64, (bf16*)smem, acc, tid);
    // core ends with __syncthreads(): LDS free for reuse

    int lane = tid & 63, wid = tid >> 6;
    int wr = (wid >> 1) * 32, wc = (wid & 1) * 32;
    int fr = lane & 15, fq = lane >> 4;
    float vv[2][2][4];
#pragma unroll
    for (int mi = 0; mi < 2; ++mi)
#pragma unroll
        for (int ni = 0; ni < 2; ++ni)
#pragma unroll
            for (int j = 0; j < 4; ++j)
                vv[mi][ni][j] = fmaxf((float)acc[mi][ni][j], 0.0f);

    // ---- stage relu(C) into Ot ----
#pragma unroll
    for (int mi = 0; mi < 2; ++mi)
#pragma unroll
        for (int ni = 0; ni < 2; ++ni)
#pragma unroll
            for (int j = 0; j < 4; ++j)
                Ot[wr + mi * 16 + fq * 4 + j][wc + ni * 16 + fr] = (bf16)vv[mi][ni][j];
    __syncthreads();
    int er = tid >> 2, ec = (tid & 3) * 16;
    size_t gbase = ((size_t)h * T + row0 + er) * NN + col0 + ec;
    bf16x8 o0 = *(bf16x8*)&Ot[er][ec];
    bf16x8 o1 = *(bf16x8*)&Ot[er][ec + 8];

    if (MODE == 0) {
        *(bf16x8*)(xs + gbase) = o0;
        *(bf16x8*)(xs + gbase + 8) = o1;
        __syncthreads();   // all LDS reads done; reuse Ot for qr
#pragma unroll
        for (int mi = 0; mi < 2; ++mi)
#pragma unroll
            for (int ni = 0; ni < 2; ++ni)
#pragma unroll
                for (int j = 0; j < 4; ++j) {
                    float v = vv[mi][ni][j];
                    float p = __shfl_xor(v, 1, 64);           // partner col n^1
                    int m = row0 + wr + mi * 16 + fq * 4 + j;
                    int n = col0 + wc + ni * 16 + fr;
                    float cs = (float)cosH[(size_t)m * (NN / 2) + (n >> 1)];
                    float sn = (float)sinH[(size_t)m * (NN / 2) + (n >> 1)];
                    float qv = v * cs + ((n & 1) ? p * sn : -p * sn);
                    Ot[wr + mi * 16 + fq * 4 + j][wc + ni * 16 + fr] = (bf16)qv;
                }
        __syncthreads();
        bf16x8 q0 = *(bf16x8*)&Ot[er][ec];
        bf16x8 q1 = *(bf16x8*)&Ot[er][ec + 8];
        *(bf16x8*)(qr + gbase) = q0;
        *(bf16x8*)(qr + gbase + 8) = q1;
    } else {
        bf16x8 x0 = *(const bf16x8*)(xs + gbase);
        bf16x8 x1 = *(const bf16x8*)(xs + gbase + 8);
        bf16x8 r0v, r1v;
#pragma unroll
        for (int k = 0; k < 8; ++k) {
            r0v[k] = (bf16)((float)o0[k] * (float)x0[k]);
            r1v[k] = (bf16)((float)o1[k] * (float)x1[k]);
        }
        *(bf16x8*)(xs + gbase) = r0v;
        *(bf16x8*)(xs + gbase + 8) = r1v;
    }
}

// ---------------- scores GEMM: spart[ks][h][t][s] (lower-tri 64-tiles) ------
// 1-D grid, 576 blocks: bid%16 = (h,ksplit) group -> XCD = bid%8 pins each
// group's panel set to one XCD's L2.
__global__ __launch_bounds__(256) void qq_mfma_k(const bf16* __restrict__ qrb,
                                                 float* __restrict__ spart) {
    __shared__ __align__(16) char smem[32768];
    int g = blockIdx.x & 15;          // (h, ksplit) group
    int h = g >> 2, ksplit = g & 3;
    int p = blockIdx.x >> 4;          // 0..35 -> (ti,tj), tj<=ti
    int ti = 0, accu = 0;
    while (accu + ti + 1 <= p) { ++ti; accu += ti; }
    int tj = p - accu;
    const bf16* Q = qrb + (size_t)h * T * NN + (size_t)ksplit * (NN / QKS);
    const bf16* Ap = Q + (size_t)(ti * 64) * NN;
    const bf16* Bp = Q + (size_t)(tj * 64) * NN;
    int tid = threadIdx.x;
    f32x4 acc[2][2];
#pragma unroll
    for (int i = 0; i < 2; ++i)
#pragma unroll
        for (int j = 0; j < 2; ++j) acc[i][j] = f32x4{0.f, 0.f, 0.f, 0.f};
    gemm_core64(Ap, NN, Bp, NN, (NN / QKS) / 64, (bf16*)smem, acc, tid);

    int lane = tid & 63, wid = tid >> 6;
    int wr = (wid >> 1) * 32, wc = (wid & 1) * 32;
    int fr = lane & 15, fq = lane >> 4;
    float* outp = spart + (size_t)(ksplit * H + h) * T * T;
#pragma unroll
    for (int mi = 0; mi < 2; ++mi)
#pragma unroll
        for (int ni = 0; ni < 2; ++ni) {
            int s = tj * 64 + wc + ni * 16 + fr;
            int mbase = ti * 64 + wr + mi * 16 + fq * 4;
#pragma unroll
            for (int j = 0; j < 4; ++j)
                outp[(size_t)(mbase + j) * T + s] = acc[mi][ni][j];
        }
}

// ---------------- sb[h][t][s] = bf16(sum_ks spart), strict causal mask ------
__global__ __launch_bounds__(256) void mask_cvt_k(const float* __restrict__ spart,
                                                  bf16* __restrict__ sb) {
    int t = blockIdx.x * 2 + (threadIdx.x >> 7);
    int h = blockIdx.y;
    int l = threadIdx.x & 127;
    int s = l * 4;
    const float* s0 = spart + ((size_t)h * T + t) * T + s;
    const size_t st = (size_t)H * T * T;
    float4 w0 = *(const float4*)(s0);
    float4 w1 = *(const float4*)(s0 + st);
    float4 w2 = *(const float4*)(s0 + 2 * st);
    float4 w3 = *(const float4*)(s0 + 3 * st);
    bf16x4 o;
    o[0] = (bf16)((s + 0 < t) ? (w0.x + w1.x + w2.x + w3.x) : 0.0f);
    o[1] = (bf16)((s + 1 < t) ? (w0.y + w1.y + w2.y + w3.y) : 0.0f);
    o[2] = (bf16)((s + 2 < t) ? (w0.z + w1.z + w2.z + w3.z) : 0.0f);
    o[3] = (bf16)((s + 3 < t) ? (w0.w + w1.w + w2.w + w3.w) : 0.0f);
    *(bf16x4*)(sb + ((size_t)h * T + t) * T + s) = o;
}

// ---------------- av: ykv_pre[h][t][d] = sum_s sb[t,s] * x[s,d] (MFMA) ------
__global__ __launch_bounds__(256) void av_mfma_k(const bf16* __restrict__ sb,
                                                 const bf16* __restrict__ xbT,
                                                 float* __restrict__ ykv_pre) {
    __shared__ __align__(16) char smem[32768];
    int h = blockIdx.z;
    int ti = blockIdx.y;
    int row0 = ti * 64, col0 = blockIdx.x * 64;
    const bf16* Ap = sb + ((size_t)h * T + row0) * T;
    const bf16* Bp = xbT + (size_t)col0 * T;
    int tid = threadIdx.x;
    f32x4 acc[2][2];
#pragma unroll
    for (int i = 0; i < 2; ++i)
#pragma unroll
        for (int j = 0; j < 2; ++j) acc[i][j] = f32x4{0.f, 0.f, 0.f, 0.f};
    // causal: sb[t][s]==0 for s>=t, so only need k < (ti+1)*64
    gemm_core64(Ap, T, Bp, T, ti + 1, (bf16*)smem, acc, tid);

    int lane = tid & 63, wid = tid >> 6;
    int wr = (wid >> 1) * 32, wc = (wid & 1) * 32;
    int fr = lane & 15, fq = lane >> 4;
#pragma unroll
    for (int mi = 0; mi < 2; ++mi)
#pragma unroll
        for (int ni = 0; ni < 2; ++ni) {
            int n = col0 + wc + ni * 16 + fr;
            int mbase = row0 + wr + mi * 16 + fq * 4;
#pragma unroll
            for (int j = 0; j < 4; ++j)
                ykv_pre[((size_t)h * T + (mbase + j)) * D + n] = acc[mi][ni][j];
        }
}

// ---------------- ykv LN: ykvb = LN(ykv_pre) --------------------------------
__global__ __launch_bounds__(256) void ykv_ln_k(const float* __restrict__ ykv_pre,
                                                bf16* __restrict__ ykvb) {
    __shared__ float red[4];
    int t = blockIdx.x, h = blockIdx.y, d = threadIdx.x;
    float a = ykv_pre[((size_t)h * T + t) * D + d];
    float m = blk_sum256(a, red) * (1.0f / D);
    float df = a - m;
    float vv = blk_sum256(df * df, red) * (1.0f / D);
    ykvb[((size_t)h * T + t) * D + d] = (bf16)(df * rsqrtf(vv + EPSF));
}

// ---------------- decoder GEMM (split-K=16, 64x64 tiles, XCD-pinned) --------
// 1-D grid, 512 blocks: ks = bid%16 -> XCD = bid%8
__global__ __launch_bounds__(256) void dec_mfma_k(const bf16* __restrict__ xyb,
                                                  const bf16* __restrict__ decT,
                                                  float* __restrict__ ypart) {
    __shared__ __align__(16) char smem[32768];
    int ks = blockIdx.x & 15;
    int t  = blockIdx.x >> 4;          // 0..31: col = t&3, row = t>>2
    int col0 = (t & 3) * 64, row0 = (t >> 2) * 64;
    int cbeg = ks * ((H * NN) / DSPLIT);   // 2048-wide slices, within one head
    int h = cbeg >> 13, n0 = cbeg & (NN - 1);
    const bf16* Ap = xyb + ((size_t)h * T + row0) * NN + n0;
    const bf16* Bp = decT + (size_t)col0 * (H * NN) + cbeg;
    int tid = threadIdx.x;
    f32x4 acc[2][2];
#pragma unroll
    for (int i = 0; i < 2; ++i)
#pragma unroll
        for (int j = 0; j < 2; ++j) acc[i][j] = f32x4{0.f, 0.f, 0.f, 0.f};
    gemm_core64(Ap, NN, Bp, H * NN, (H * NN / DSPLIT) / 64, (bf16*)smem, acc, tid);

    int lane = tid & 63, wid = tid >> 6;
    int wr = (wid >> 1) * 32, wc = (wid & 1) * 32;
    int fr = lane & 15, fq = lane >> 4;
#pragma unroll
    for (int mi = 0; mi < 2; ++mi)
#pragma unroll
        for (int ni = 0; ni < 2; ++ni) {
            int n = col0 + wc + ni * 16 + fr;
            int mbase = row0 + wr + mi * 16 + fq * 4;
#pragma unroll
            for (int j = 0; j < 4; ++j)
                ypart[((size_t)ks * T + (mbase + j)) * D + n] = acc[mi][ni][j];
        }
}

// ---------------- y = LN(sum ypart); x = LN(x + y); bf16 + bf16^T copies ----
__global__ __launch_bounds__(256) void final_ln_k(const float* __restrict__ ypart,
                                                  float* __restrict__ x,
                                                  bf16* __restrict__ xb,
                                                  bf16* __restrict__ xbT) {
    __shared__ float red[4];
    int t = blockIdx.x, d = threadIdx.x;
    float ys = 0.0f;
#pragma unroll
    for (int ks = 0; ks < DSPLIT; ++ks) ys += ypart[((size_t)ks * T + t) * D + d];
    float m = blk_sum256(ys, red) * (1.0f / D);
    float df = ys - m;
    float vv = blk_sum256(df * df, red) * (1.0f / D);
    float yln = df * rsqrtf(vv + EPSF);
    float val = x[(size_t)t * D + d] + yln;
    float m2 = blk_sum256(val, red) * (1.0f / D);
    float df2 = val - m2;
    float v2 = blk_sum256(df2 * df2, red) * (1.0f / D);
    float r = df2 * rsqrtf(v2 + EPSF);
    x[(size_t)t * D + d] = r;
    xb[(size_t)t * D + d] = (bf16)r;
    xbT[(size_t)d * T + t] = (bf16)r;
}

// ---------------- logits = x @ lm_head (f32) --------------------------------
__global__ __launch_bounds__(256) void logits_k(const float* __restrict__ x,
                                                const float* __restrict__ lm,
                                                float* __restrict__ out) {
    int t = blockIdx.x, v = threadIdx.x;
    float a = 0.0f;
    for (int d = 0; d < D; ++d)
        a = fmaf(x[(size_t)t * D + d], lm[(size_t)d * V + v], a);
    out[(size_t)t * V + v] = a;
}

extern "C" void kernel_launch(void* const* d_in, const int* in_sizes, int n_in,
                              void* d_out, int out_size, void* d_ws, size_t ws_size,
                              hipStream_t stream) {
    const int*   idx       = (const int*)d_in[0];
    const float* embed     = (const float*)d_in[1];
    const float* encoder   = (const float*)d_in[2];
    const float* encoder_v = (const float*)d_in[3];
    const float* decoder   = (const float*)d_in[4];
    const float* lm_head   = (const float*)d_in[5];
    float* out = (float*)d_out;

    // ---- workspace layout (~146 MB) ----
    char* W = (char*)d_ws;
    float* x       = (float*)W; W += (size_t)T * D * 4;
    float* scratch = (float*)W; W += (size_t)QKS * H * T * T * 4;  // spart / ykv_pre / ypart union
    bf16* xb    = (bf16*)W; W += (size_t)T * D * 2;
    bf16* xbT   = (bf16*)W; W += (size_t)D * T * 2;
    bf16* sb    = (bf16*)W; W += (size_t)H * T * T * 2;
    bf16* ykvb  = (bf16*)W; W += (size_t)H * T * D * 2;
    bf16* encT  = (bf16*)W; W += (size_t)H * NN * D * 2;
    bf16* encVT = (bf16*)W; W += (size_t)H * NN * D * 2;
    bf16* decT  = (bf16*)W; W += (size_t)D * H * NN * 2;
    bf16* cosH  = (bf16*)W; W += (size_t)T * (NN / 2) * 2;
    bf16* sinH  = (bf16*)W; W += (size_t)T * (NN / 2) * 2;
    bf16* xs    = (bf16*)W; W += (size_t)H * T * NN * 2;
    bf16* qr    = (bf16*)W; W += (size_t)H * T * NN * 2;

    // ---- one-time per launch: weight transpose+convert, RoPE tables ----
    tcvt_k<<<dim3(NN / 32, D / 32, H), 256, 0, stream>>>(encoder, encT, D, NN);
    tcvt_k<<<dim3(NN / 32, D / 32, H), 256, 0, stream>>>(encoder_v, encVT, D, NN);
    tcvt_k<<<dim3(D / 32, (H * NN) / 32, 1), 256, 0, stream>>>(decoder, decT, H * NN, D);
    rope_tab_k<<<dim3((NN / 2) / 256, T), 256, 0, stream>>>(cosH, sinH);

    embed_ln_k<<<T, 256, 0, stream>>>(idx, embed, x, xb, xbT);

    for (int layer = 0; layer < N_LAYER; ++layer) {
        enc_mfma_k<0><<<dim3(NN / 64, T / 64, H), 256, 0, stream>>>(
            xb, encT, xs, qr, cosH, sinH, 0);
        qq_mfma_k<<<576, 256, 0, stream>>>(qr, scratch);
        mask_cvt_k<<<dim3(T / 2, H), 256, 0, stream>>>(scratch, sb);
        av_mfma_k<<<dim3(D / 64, T / 64, H), 256, 0, stream>>>(sb, xbT, scratch);
        ykv_ln_k<<<dim3(T, H), 256, 0, stream>>>(scratch, ykvb);
        enc_mfma_k<1><<<dim3(NN / 64, T / 64, H), 256, 0, stream>>>(
            ykvb, encVT, xs, nullptr, nullptr, nullptr, T * D);
        dec_mfma_k<<<512, 256, 0, stream>>>(xs, decT, scratch);
        final_ln_k<<<T, 256, 0, stream>>>(scratch, x, xb, xbT);
    }

    logits_k<<<T, 256, 0, stream>>>(x, lm_head, out);
}